// Round 7
// baseline (528.217 us; speedup 1.0000x reference)
//
#include <hip/hip_runtime.h>
#include <math.h>

// Problem constants (B=2, T=2048, C=2048, NH=16, HS=128, N_ELEM=64, A_T=10)
#define B_DIM 2
#define T_DIM 2048
#define C_DIM 2048
#define NHEAD 16
#define HS 128
#define QKV_N 6144          // 3*C
#define AT 10
#define M_DIM 4096          // B*T

using bf16x8 = __attribute__((ext_vector_type(8))) short;
using f32x4v = __attribute__((ext_vector_type(4))) float;

__device__ __forceinline__ unsigned short f2bf(float f) {
    union { float f; unsigned int u; } cv; cv.f = f;
    unsigned int u = cv.u;
    return (unsigned short)((u + 0x7FFFu + ((u >> 16) & 1u)) >> 16);
}
__device__ __forceinline__ float bf2f(unsigned short h) {
    union { unsigned int u; float f; } cv; cv.u = ((unsigned int)h) << 16;
    return cv.f;
}
__device__ __forceinline__ unsigned int pack_bf16(float lo, float hi) {
    unsigned int r;
    asm volatile("v_cvt_pk_bf16_f32 %0, %1, %2" : "=v"(r) : "v"(lo), "v"(hi));
    return r;
}
__device__ __forceinline__ void gload_lds16(const void* g, void* l) {
    __builtin_amdgcn_global_load_lds(
        (const __attribute__((address_space(1))) void*)g,
        (__attribute__((address_space(3))) void*)l, 16, 0, 0);
}

// ---------------------------------------------------------------------------
// f32 -> bf16 convert (8 elems/thread)
// ---------------------------------------------------------------------------
__global__ __launch_bounds__(256)
void f32_to_bf16_kernel(const float* __restrict__ in, unsigned short* __restrict__ out, int n8) {
    const int i = blockIdx.x * 256 + threadIdx.x;
    if (i >= n8) return;
    const float4 a = *(const float4*)&in[(size_t)i * 8];
    const float4 b = *(const float4*)&in[(size_t)i * 8 + 4];
    *(ushort4*)&out[(size_t)i * 8]     = make_ushort4(f2bf(a.x), f2bf(a.y), f2bf(a.z), f2bf(a.w));
    *(ushort4*)&out[(size_t)i * 8 + 4] = make_ushort4(f2bf(b.x), f2bf(b.y), f2bf(b.z), f2bf(b.w));
}

// ---------------------------------------------------------------------------
// Pipelined bf16 MFMA GEMM NT (R7): C = A[M][K]*B[N][K]^T + bias.
//  - 128x128 tile, BK=32, 4 waves; 3 LDS buffers, depth-2 prefetch, counted
//    s_waitcnt vmcnt(4) + raw s_barrier (ONE barrier per K-step).
//  - R7 FIX: conflict-free LDS via [seg][granule][row] layout — staging lane L
//    fetches global (row = L&15, k-granule = L>>4) so the linear
//    global_load_lds write produces granule-major LDS; a fragment read
//    (16 lanes, same granule) is then 256B CONTIGUOUS (was: 4-way conflict,
//    R6's XOR over 4 granules couldn't fix rows 0/4/8/12 aliasing).
//  - grouped (G=8) + XCD-chunked block swizzle for L2 locality.
// FUSED=0: f32 out + bias (proj GEMM).
// FUSED=1: qkv epilogue — bias + RoPE on q/k + direct write to Qb/Kb
//          [bh][T][128] and V transposed into Vt [bh][128][T].
// ---------------------------------------------------------------------------
template<int FUSED>
__global__ __launch_bounds__(256)
void gemm_pipe(const unsigned short* __restrict__ A, const unsigned short* __restrict__ Bw,
               const float* __restrict__ bias, float* __restrict__ Cf32,
               const float* __restrict__ cosb, const float* __restrict__ sinb,
               unsigned short* __restrict__ Qb, unsigned short* __restrict__ Kb,
               unsigned short* __restrict__ Vt, int M, int N, int K) {
    __shared__ unsigned short As[3][4096];   // 3 x 8KB, layout [seg][gran][row]
    __shared__ unsigned short Bs[3][4096];

    const int tid  = threadIdx.x;
    const int wave = tid >> 6;
    const int lane = tid & 63;

    // XCD chunking + grouped (G=8 n-tiles) mapping for L2 locality
    const int ncnt = gridDim.x, mcnt = gridDim.y;
    const int nwg = ncnt * mcnt;
    int bid = blockIdx.y * ncnt + blockIdx.x;
    bid = (bid & 7) * (nwg >> 3) + (bid >> 3);          // per-XCD contiguous chunks
    const int mt = (bid >> 3) % mcnt;
    const int nt = (bid / (mcnt * 8)) * 8 + (bid & 7);  // G=8 column groups
    const int m0 = mt * 128, n0 = nt * 128;

    const int wr = (wave >> 1) * 64;
    const int wc = (wave & 1) * 64;
    const int fr = lane & 15;
    const int hi = lane >> 4;

    // staging: lane covers row (lane&15) of the segment, k-granule (lane>>4)
    const int srow = lane & 15;
    const int sk   = 8 * (lane >> 4);

    auto STAGE = [&](int ks, int bi) {
        const int k0 = ks << 5;
#pragma unroll
        for (int t = 0; t < 2; ++t) {
            const int seg = wave * 2 + t;
            gload_lds16(&A[(size_t)(m0 + seg * 16 + srow) * K + k0 + sk], &As[bi][seg * 512]);
            gload_lds16(&Bw[(size_t)(n0 + seg * 16 + srow) * K + k0 + sk], &Bs[bi][seg * 512]);
        }
    };

    f32x4v acc[4][4];
#pragma unroll
    for (int i = 0; i < 4; ++i)
#pragma unroll
        for (int j = 0; j < 4; ++j)
#pragma unroll
            for (int q = 0; q < 4; ++q) acc[i][j][q] = 0.f;

    const int nk = K >> 5;
    STAGE(0, 0);
    STAGE(1, 1);

    // fragment read offset within a segment: granule hi, row fr (shorts)
    const int foff = hi * 128 + fr * 8;
    const int aseg = (wave >> 1) * 4;    // first A segment of this wave
    const int bseg = (wave & 1) * 4;     // first B segment of this wave

    for (int ks = 0; ks < nk; ++ks) {
        // wait for buf[ks]'s loads (issued 2 steps ago); keep later stages in flight
        if (ks < nk - 1) asm volatile("s_waitcnt vmcnt(4)" ::: "memory");
        else             asm volatile("s_waitcnt vmcnt(0)" ::: "memory");
        __builtin_amdgcn_sched_barrier(0);
        __builtin_amdgcn_s_barrier();            // all waves' buf[ks] loads done;
        asm volatile("" ::: "memory");           //  buf[ks-1] readers all finished
        __builtin_amdgcn_sched_barrier(0);

        const unsigned short* Ab = As[ks % 3];
        const unsigned short* Bb = Bs[ks % 3];
        bf16x8 af[4], bfg[4];
#pragma unroll
        for (int i = 0; i < 4; ++i)
            af[i] = *(const bf16x8*)&Ab[(aseg + i) * 512 + foff];
#pragma unroll
        for (int j = 0; j < 4; ++j)
            bfg[j] = *(const bf16x8*)&Bb[(bseg + j) * 512 + foff];

        if (ks + 2 < nk) STAGE(ks + 2, (ks + 2) % 3);   // overwrites buf[ks-1]

        __builtin_amdgcn_s_setprio(1);
#pragma unroll
        for (int i = 0; i < 4; ++i)
#pragma unroll
            for (int j = 0; j < 4; ++j)
                acc[i][j] = __builtin_amdgcn_mfma_f32_16x16x32_bf16(af[i], bfg[j], acc[i][j], 0, 0, 0);
        __builtin_amdgcn_s_setprio(0);
    }

    const int r4 = hi * 4;
    if constexpr (FUSED) {
        const int part = (n0 >> 7) % 3;          // 0=q 1=k 2=v
        const int head = n0 / 384;
        const int bh   = (m0 >> 11) * NHEAD + head;
        if (part == 2) {
            // V: transposed write, 4 consecutive t per frag -> ushort4
#pragma unroll
            for (int i = 0; i < 4; ++i) {
                const int t0v = (m0 & (T_DIM - 1)) + wr + i * 16 + r4;
#pragma unroll
                for (int j = 0; j < 4; ++j) {
                    const int d = wc + j * 16 + fr;
                    const float bv = bias[n0 + d];
                    ushort4 o = make_ushort4(f2bf(acc[i][j][0] + bv), f2bf(acc[i][j][1] + bv),
                                             f2bf(acc[i][j][2] + bv), f2bf(acc[i][j][3] + bv));
                    *(ushort4*)&Vt[((size_t)bh * HS + d) * T_DIM + t0v] = o;
                }
            }
        } else {
            unsigned short* Dst = part ? Kb : Qb;
            if (wc == 0) {
                // rope lanes: cols d=j*16+fr (j<2) paired with d+32 (j+2)
#pragma unroll
                for (int i = 0; i < 4; ++i) {
#pragma unroll
                    for (int q = 0; q < 4; ++q) {
                        const int t = (m0 & (T_DIM - 1)) + wr + i * 16 + r4 + q;
                        const float* crow = &cosb[t * 64];
                        const float* srw  = &sinb[t * 64];
                        unsigned short* drow = &Dst[((size_t)bh * T_DIM + t) * HS];
#pragma unroll
                        for (int j = 0; j < 2; ++j) {
                            const int d = j * 16 + fr;
                            const float v1 = acc[i][j][q]     + bias[n0 + d];
                            const float v2 = acc[i][j + 2][q] + bias[n0 + d + 32];
                            drow[d]      = f2bf(v1 * crow[d]      - v2 * srw[d]);
                            drow[d + 32] = f2bf(v2 * crow[d + 32] + v1 * srw[d + 32]);
                        }
                    }
                }
            } else {
                // non-rope lanes: d = 64 + j*16 + fr
#pragma unroll
                for (int i = 0; i < 4; ++i) {
                    const int t0r = (m0 & (T_DIM - 1)) + wr + i * 16 + r4;
#pragma unroll
                    for (int j = 0; j < 4; ++j) {
                        const int d = 64 + j * 16 + fr;
                        const float bv = bias[n0 + d];
                        unsigned short* dcol = &Dst[((size_t)bh * T_DIM + t0r) * HS + d];
#pragma unroll
                        for (int q = 0; q < 4; ++q)
                            dcol[(size_t)q * HS] = f2bf(acc[i][j][q] + bv);
                    }
                }
            }
        }
    } else {
#pragma unroll
        for (int i = 0; i < 4; ++i) {
#pragma unroll
            for (int j = 0; j < 4; ++j) {
                const int col = n0 + wc + j * 16 + fr;
                const float bv = bias[col];
#pragma unroll
                for (int q = 0; q < 4; ++q) {
                    const int row = m0 + wr + i * 16 + r4 + q;
                    Cf32[(size_t)row * N + col] = acc[i][j][q] + bv;
                }
            }
        }
    }
}

// ---------------------------------------------------------------------------
// adapter qkv (tiny GEMM, bf16 weights; verified R5)
// ---------------------------------------------------------------------------
__global__ __launch_bounds__(64)
void adapter_qkv_kernel(const float* __restrict__ wte, const unsigned short* __restrict__ wb,
                        const float* __restrict__ bias, float* __restrict__ aqkv) {
    const int n = blockIdx.x;
    const int lane = threadIdx.x;
    float acc[AT];
#pragma unroll
    for (int a = 0; a < AT; ++a) acc[a] = 0.f;
    for (int k = lane * 8; k < C_DIM; k += 64 * 8) {
        const ushort4 wa = *(const ushort4*)&wb[(size_t)n * C_DIM + k];
        const ushort4 wc = *(const ushort4*)&wb[(size_t)n * C_DIM + k + 4];
        const float w0 = bf2f(wa.x), w1 = bf2f(wa.y), w2 = bf2f(wa.z), w3 = bf2f(wa.w);
        const float w4 = bf2f(wc.x), w5 = bf2f(wc.y), w6 = bf2f(wc.z), w7 = bf2f(wc.w);
#pragma unroll
        for (int a = 0; a < AT; ++a) {
            const float4 t0 = *(const float4*)&wte[(size_t)a * C_DIM + k];
            const float4 t1 = *(const float4*)&wte[(size_t)a * C_DIM + k + 4];
            acc[a] += w0 * t0.x + w1 * t0.y + w2 * t0.z + w3 * t0.w
                    + w4 * t1.x + w5 * t1.y + w6 * t1.z + w7 * t1.w;
        }
    }
#pragma unroll
    for (int a = 0; a < AT; ++a) {
        float v = acc[a];
        for (int off = 32; off; off >>= 1) v += __shfl_down(v, off);
        if (lane == 0) aqkv[(size_t)a * QKV_N + n] = v + bias[n];
    }
}

// ---------------------------------------------------------------------------
// MFMA flash causal attention (verified R5/R6): qt-paired blocks, dbuf staging,
// log2-domain online softmax with defer-max, in-register P redistribution,
// fused adapter attention (BLOCKED aqkv layout), setprio around MFMA.
// ---------------------------------------------------------------------------
__global__ __launch_bounds__(256)
void flash_mfma(const unsigned short* __restrict__ Qb, const unsigned short* __restrict__ Kb,
                const unsigned short* __restrict__ Vt, const float* __restrict__ aqkv,
                const float* __restrict__ gating, unsigned short* __restrict__ yb) {
    __shared__ __align__(16) unsigned short smem[2][16384];   // [buf][K:8192 | V:8192]

    const int tid = threadIdx.x;
    const int wave = tid >> 6, lane = tid & 63;
    const int lo = lane & 15, hi = lane >> 4;

    const int z = blockIdx.x & 15;
    const int h = (blockIdx.x >> 4) & 15;
    const int b = blockIdx.x >> 8;
    const int bh = b * NHEAD + h;
    const float kscale = 0.08838834764831845f * 1.4426950408889634f;  // scale*log2(e)

    const unsigned short* Qh = Qb + (size_t)bh * T_DIM * HS;
    const unsigned short* Kh = Kb + (size_t)bh * T_DIM * HS;
    const unsigned short* Vh = Vt + (size_t)bh * HS * T_DIM;

    float* AK = (float*)&smem[0][0];     // adapter overlay (10x128 f32 x2 = 10KB)
    float* AV = AK + AT * HS;

    auto STAGE = [&](int k0, int bufi) {
        unsigned short* Kd = &smem[bufi][0];
        unsigned short* Vd = &smem[bufi][8192];
#pragma unroll
        for (int t = 0; t < 4; ++t) {
            const int kr = wave * 16 + t * 4 + hi;
            gload_lds16(Kh + (size_t)(k0 + kr) * HS + 8 * (lo ^ (kr & 7)),
                        &Kd[(wave * 16 + t * 4) * 128]);
            const int vr = (wave * 4 + t) * 8 + (lane >> 3);
            gload_lds16(Vh + (size_t)vr * T_DIM + k0 + 8 * ((lane & 7) ^ (vr & 7)),
                        &Vd[(wave * 4 + t) * 8 * 64]);
        }
    };

#pragma unroll 1
    for (int pass = 0; pass < 2; ++pass) {
        const int qt = pass ? z : (31 - z);
        const int q0 = qt * 64;
        const int myqrow = q0 + wave * 16 + lo;

        bf16x8 qf[4];
        {
            const unsigned short* qrow = Qh + (size_t)myqrow * HS;
#pragma unroll
            for (int c = 0; c < 4; ++c) qf[c] = *(const bf16x8*)&qrow[c * 32 + hi * 8];
        }

        f32x4v oacc[8];
#pragma unroll
        for (int d = 0; d < 8; ++d)
#pragma unroll
            for (int q = 0; q < 4; ++q) oacc[d][q] = 0.f;
        float m = -INFINITY, ln = 0.f;

        STAGE(0, 0);
        int cur = 0;
        for (int kt = 0; kt <= qt; ++kt) {
            const int k0 = kt * 64;
            __syncthreads();
            if (kt < qt) STAGE(k0 + 64, cur ^ 1);
            const unsigned short* Ks = &smem[cur][0];
            const unsigned short* Vs = &smem[cur][8192];

            f32x4v sacc[4];
            __builtin_amdgcn_s_setprio(1);
#pragma unroll
            for (int s = 0; s < 4; ++s) {
#pragma unroll
                for (int q = 0; q < 4; ++q) sacc[s][q] = 0.f;
                const int krow = s * 16 + lo;
                const int rs = (lo & 7) << 4;
#pragma unroll
                for (int c = 0; c < 4; ++c) {
                    const int boff = (c * 64 + hi * 16) ^ rs;
                    bf16x8 kf = *(const bf16x8*)&Ks[krow * 128 + (boff >> 1)];
                    sacc[s] = __builtin_amdgcn_mfma_f32_16x16x32_bf16(kf, qf[c], sacc[s], 0, 0, 0);
                }
            }
            __builtin_amdgcn_s_setprio(0);

            const bool dtile = (kt == qt);
            float p[4][4];
            float xm = -INFINITY;
#pragma unroll
            for (int s = 0; s < 4; ++s)
#pragma unroll
                for (int q = 0; q < 4; ++q) {
                    float v = sacc[s][q] * kscale;
                    if (dtile && (k0 + s * 16 + hi * 4 + q > myqrow)) v = -INFINITY;
                    p[s][q] = v;
                    xm = fmaxf(xm, v);
                }
            xm = fmaxf(xm, __shfl_xor(xm, 16));
            xm = fmaxf(xm, __shfl_xor(xm, 32));
            if (__any(xm > m + 11.5f)) {
                const float mnew = fmaxf(m, xm);
                const float al = exp2f(m - mnew);
                m = mnew;
                ln *= al;
                float aq[4];
#pragma unroll
                for (int q = 0; q < 4; ++q) aq[q] = __shfl(al, hi * 4 + q);
#pragma unroll
                for (int d = 0; d < 8; ++d)
#pragma unroll
                    for (int q = 0; q < 4; ++q) oacc[d][q] *= aq[q];
            }
            float psum = 0.f;
#pragma unroll
            for (int s = 0; s < 4; ++s)
#pragma unroll
                for (int q = 0; q < 4; ++q) {
                    p[s][q] = exp2f(p[s][q] - m);
                    psum += p[s][q];
                }
            psum += __shfl_xor(psum, 16);
            psum += __shfl_xor(psum, 32);
            ln += psum;

            unsigned int pk[4][2];
#pragma unroll
            for (int s = 0; s < 4; ++s) {
                pk[s][0] = pack_bf16(p[s][0], p[s][1]);
                pk[s][1] = pack_bf16(p[s][2], p[s][3]);
            }
            const int src0 = lo + ((hi & 1) << 5);
            const int src1 = src0 + 16;
            const bool shi = (hi >> 1) != 0;
#pragma unroll
            for (int c = 0; c < 2; ++c) {
                const unsigned int a0 = (unsigned int)__shfl((int)pk[c*2][0], src0);
                const unsigned int b0 = (unsigned int)__shfl((int)pk[c*2+1][0], src0);
                const unsigned int a1 = (unsigned int)__shfl((int)pk[c*2][1], src0);
                const unsigned int b1 = (unsigned int)__shfl((int)pk[c*2+1][1], src0);
                const unsigned int a2 = (unsigned int)__shfl((int)pk[c*2][0], src1);
                const unsigned int b2 = (unsigned int)__shfl((int)pk[c*2+1][0], src1);
                const unsigned int a3 = (unsigned int)__shfl((int)pk[c*2][1], src1);
                const unsigned int b3 = (unsigned int)__shfl((int)pk[c*2+1][1], src1);
                union { unsigned int u[4]; bf16x8 v; } cv2;
                cv2.u[0] = shi ? b0 : a0;
                cv2.u[1] = shi ? b1 : a1;
                cv2.u[2] = shi ? b2 : a2;
                cv2.u[3] = shi ? b3 : a3;
                const bf16x8 pf = cv2.v;
                __builtin_amdgcn_s_setprio(1);
#pragma unroll
                for (int d = 0; d < 8; ++d) {
                    const int vrow = d * 16 + lo;
                    const int boff = (c * 64 + hi * 16) ^ ((lo & 7) << 4);
                    bf16x8 vf = *(const bf16x8*)&Vs[vrow * 64 + (boff >> 1)];
                    oacc[d] = __builtin_amdgcn_mfma_f32_16x16x32_bf16(pf, vf, oacc[d], 0, 0, 0);
                }
                __builtin_amdgcn_s_setprio(0);
            }
            cur ^= 1;
        }

        float linv[4];
#pragma unroll
        for (int q = 0; q < 4; ++q) linv[q] = 1.f / __shfl(ln, hi * 4 + q);
#pragma unroll
        for (int d = 0; d < 8; ++d)
#pragma unroll
            for (int q = 0; q < 4; ++q) oacc[d][q] *= linv[q];

        // ---- adapter attention (10 keys, unmasked; BLOCKED aqkv layout) ----
        __syncthreads();
        for (int idx = tid; idx < AT * HS; idx += 256) {
            const int a = idx >> 7, d = idx & 127;
            AK[idx] = aqkv[(size_t)a * QKV_N + C_DIM + h * HS + d];
            AV[idx] = aqkv[(size_t)a * QKV_N + 2 * C_DIM + h * HS + d];
        }
        __syncthreads();

        float qflt[4][8];
#pragma unroll
        for (int c = 0; c < 4; ++c)
#pragma unroll
            for (int j = 0; j < 8; ++j) qflt[c][j] = bf2f((unsigned short)qf[c][j]);

        float e[AT];
        float amax = -INFINITY;
#pragma unroll
        for (int a = 0; a < AT; ++a) {
            float t = 0.f;
#pragma unroll
            for (int c = 0; c < 4; ++c) {
                const float4 k0v = *(const float4*)&AK[a * HS + c * 32 + hi * 8];
                const float4 k1v = *(const float4*)&AK[a * HS + c * 32 + hi * 8 + 4];
                t += qflt[c][0] * k0v.x + qflt[c][1] * k0v.y + qflt[c][2] * k0v.z + qflt[c][3] * k0v.w
                   + qflt[c][4] * k1v.x + qflt[c][5] * k1v.y + qflt[c][6] * k1v.z + qflt[c][7] * k1v.w;
            }
            t += __shfl_xor(t, 16);
            t += __shfl_xor(t, 32);
            e[a] = t * 0.08838834764831845f;
            amax = fmaxf(amax, e[a]);
        }
        float asum = 0.f;
#pragma unroll
        for (int a = 0; a < AT; ++a) { e[a] = __expf(e[a] - amax); asum += e[a]; }
        const float gcoef = gating[0] / asum;

#pragma unroll
        for (int a = 0; a < AT; ++a) {
            const float ca = e[a] * gcoef;
            float cq[4];
#pragma unroll
            for (int q = 0; q < 4; ++q) cq[q] = __shfl(ca, hi * 4 + q);
#pragma unroll
            for (int d = 0; d < 8; ++d) {
                const float av = AV[a * HS + d * 16 + lo];
#pragma unroll
                for (int q = 0; q < 4; ++q) oacc[d][q] += cq[q] * av;
            }
        }

#pragma unroll
        for (int q = 0; q < 4; ++q) {
            const int row = q0 + wave * 16 + hi * 4 + q;
            unsigned short* dst = yb + ((size_t)(b * T_DIM + row)) * C_DIM + h * HS + lo;
#pragma unroll
            for (int d = 0; d < 8; ++d) dst[d * 16] = f2bf(oacc[d][q]);
        }

        if (pass == 0) __syncthreads();
    }
}

// ---------------------------------------------------------------------------
extern "C" void kernel_launch(void* const* d_in, const int* in_sizes, int n_in,
                              void* d_out, int out_size, void* d_ws, size_t ws_size,
                              hipStream_t stream) {
    const float* x       = (const float*)d_in[0];
    const float* cosb    = (const float*)d_in[1];
    const float* sinb    = (const float*)d_in[2];
    // d_in[3] = mask (causal, unused)
    const float* attn_w  = (const float*)d_in[4];
    const float* attn_b  = (const float*)d_in[5];
    const float* proj_w  = (const float*)d_in[6];
    const float* proj_b  = (const float*)d_in[7];
    const float* wte     = (const float*)d_in[8];
    const float* gating  = (const float*)d_in[9];
    float* out = (float*)d_out;

    // workspace (~118 MB): aqkv | xb | awb | Qb | Kb | Vt | pwb | yv
    float* aqkv = (float*)d_ws;
    unsigned short* xb  = (unsigned short*)(aqkv + (size_t)AT * QKV_N);
    unsigned short* awb = xb  + (size_t)M_DIM * C_DIM;
    unsigned short* Qb  = awb + (size_t)QKV_N * C_DIM;
    unsigned short* Kb  = Qb  + (size_t)B_DIM * NHEAD * T_DIM * HS;
    unsigned short* Vt  = Kb  + (size_t)B_DIM * NHEAD * T_DIM * HS;
    unsigned short* pwb = Vt  + (size_t)B_DIM * NHEAD * T_DIM * HS;
    unsigned short* yv  = pwb + (size_t)C_DIM * C_DIM;

    // 1. convert x, attn_w to bf16
    f32_to_bf16_kernel<<<(M_DIM * C_DIM / 8 + 255) / 256, 256, 0, stream>>>(x, xb, M_DIM * C_DIM / 8);
    f32_to_bf16_kernel<<<(QKV_N * C_DIM / 8 + 255) / 256, 256, 0, stream>>>(attn_w, awb, QKV_N * C_DIM / 8);
    // 2. fused qkv GEMM: bias + RoPE + repack -> Qb/Kb/Vt directly
    gemm_pipe<1><<<dim3(QKV_N / 128, M_DIM / 128), 256, 0, stream>>>(
        xb, awb, attn_b, nullptr, cosb, sinb, Qb, Kb, Vt, M_DIM, QKV_N, C_DIM);
    // 3. adapter qkv (bf16 weights)
    adapter_qkv_kernel<<<QKV_N, 64, 0, stream>>>(wte, awb, attn_b, aqkv);
    // 4. convert proj_w
    f32_to_bf16_kernel<<<(C_DIM * C_DIM / 8 + 255) / 256, 256, 0, stream>>>(proj_w, pwb, C_DIM * C_DIM / 8);
    // 5. MFMA flash attention + adapter + gating -> yv (bf16)
    flash_mfma<<<B_DIM * NHEAD * 16, 256, 0, stream>>>(Qb, Kb, Vt, aqkv, gating, yv);
    // 6. out = y @ proj_w^T + proj_b (f32 out)
    gemm_pipe<0><<<dim3(C_DIM / 128, M_DIM / 128), 256, 0, stream>>>(
        yv, pwb, proj_b, out, nullptr, nullptr, nullptr, nullptr, nullptr, M_DIM, C_DIM, C_DIM);
}

// Round 8
// 437.100 us; speedup vs baseline: 1.2085x; 1.2085x over previous
//
#include <hip/hip_runtime.h>
#include <math.h>

// Problem constants (B=2, T=2048, C=2048, NH=16, HS=128, N_ELEM=64, A_T=10)
#define B_DIM 2
#define T_DIM 2048
#define C_DIM 2048
#define NHEAD 16
#define HS 128
#define QKV_N 6144          // 3*C
#define AT 10
#define M_DIM 4096          // B*T

using bf16x8 = __attribute__((ext_vector_type(8))) short;
using f32x4v = __attribute__((ext_vector_type(4))) float;

__device__ __forceinline__ unsigned short f2bf(float f) {
    union { float f; unsigned int u; } cv; cv.f = f;
    unsigned int u = cv.u;
    return (unsigned short)((u + 0x7FFFu + ((u >> 16) & 1u)) >> 16);
}
__device__ __forceinline__ float bf2f(unsigned short h) {
    union { unsigned int u; float f; } cv; cv.u = ((unsigned int)h) << 16;
    return cv.f;
}
__device__ __forceinline__ unsigned int pack_bf16(float lo, float hi) {
    unsigned int r;
    asm volatile("v_cvt_pk_bf16_f32 %0, %1, %2" : "=v"(r) : "v"(lo), "v"(hi));
    return r;
}
__device__ __forceinline__ void gload_lds16(const void* g, void* l) {
    __builtin_amdgcn_global_load_lds(
        (const __attribute__((address_space(1))) void*)g,
        (__attribute__((address_space(3))) void*)l, 16, 0, 0);
}

// ---------------------------------------------------------------------------
// f32 -> bf16 convert (8 elems/thread)
// ---------------------------------------------------------------------------
__global__ __launch_bounds__(256)
void f32_to_bf16_kernel(const float* __restrict__ in, unsigned short* __restrict__ out, int n8) {
    const int i = blockIdx.x * 256 + threadIdx.x;
    if (i >= n8) return;
    const float4 a = *(const float4*)&in[(size_t)i * 8];
    const float4 b = *(const float4*)&in[(size_t)i * 8 + 4];
    *(ushort4*)&out[(size_t)i * 8]     = make_ushort4(f2bf(a.x), f2bf(a.y), f2bf(a.z), f2bf(a.w));
    *(ushort4*)&out[(size_t)i * 8 + 4] = make_ushort4(f2bf(b.x), f2bf(b.y), f2bf(b.z), f2bf(b.w));
}

// ---------------------------------------------------------------------------
// Pipelined bf16 MFMA GEMM NT (R8): C = A[M][K]*B[N][K]^T + bias.
//  - 128x128 tile, BK=32, 4 waves; 3 LDS buffers, depth-2 prefetch, counted
//    s_waitcnt vmcnt(4) + raw s_barrier (ONE barrier per K-step).
//  - R8: COALESCED staging (R6 pattern: 4 lanes cover one row's 64B) with
//    CORRECTED granule XOR g ^= (row>>1)&3. Bank model (validated on R5/R6/R7
//    counters): read slot%8 = (fr&1)*4 + g'; old (row&3) XOR left fr/fr+4
//    colliding ((fr+4)&3==fr&3 -> 1.26e7 conflicts); (fr>>1)&3 makes all 8
//    lanes of each read phase distinct. R7's granule-major layout had 0
//    conflicts but scattered global 16B reads (4KB lane stride) -> 211us.
//  - grouped (G=8) + XCD-chunked block swizzle for L2 locality.
// FUSED=0: f32 out + bias (proj GEMM).
// FUSED=1: qkv epilogue — bias + RoPE on q/k + direct write to Qb/Kb
//          [bh][T][128] and V transposed into Vt [bh][128][T].
// ---------------------------------------------------------------------------
template<int FUSED>
__global__ __launch_bounds__(256)
void gemm_pipe(const unsigned short* __restrict__ A, const unsigned short* __restrict__ Bw,
               const float* __restrict__ bias, float* __restrict__ Cf32,
               const float* __restrict__ cosb, const float* __restrict__ sinb,
               unsigned short* __restrict__ Qb, unsigned short* __restrict__ Kb,
               unsigned short* __restrict__ Vt, int M, int N, int K) {
    __shared__ unsigned short As[3][4096];   // 3 x 8KB, rows 64B, granule-XOR'd
    __shared__ unsigned short Bs[3][4096];

    const int tid  = threadIdx.x;
    const int wave = tid >> 6;
    const int lane = tid & 63;

    // XCD chunking + grouped (G=8 n-tiles) mapping for L2 locality
    const int ncnt = gridDim.x, mcnt = gridDim.y;
    const int nwg = ncnt * mcnt;
    int bid = blockIdx.y * ncnt + blockIdx.x;
    bid = (bid & 7) * (nwg >> 3) + (bid >> 3);          // per-XCD contiguous chunks
    const int mt = (bid >> 3) % mcnt;
    const int nt = (bid / (mcnt * 8)) * 8 + (bid & 7);  // G=8 column groups
    const int m0 = mt * 128, n0 = nt * 128;

    const int wr = (wave >> 1) * 64;
    const int wc = (wave & 1) * 64;
    const int fr = lane & 15;
    const int hi = lane >> 4;

    // staging: lane covers row (lane>>2) of segment, 16B granule (lane&3),
    // source granule XOR'd by (row>>1)&3  (row = lane>>2 within segment)
    const int srow = lane >> 2;
    const int sk   = 8 * ((lane & 3) ^ ((lane >> 3) & 3));
    // fragment read: global k-granule hi of row fr lives at LDS granule
    // hi ^ ((fr>>1)&3)
    const int swk  = 8 * (hi ^ ((fr >> 1) & 3));

    auto STAGE = [&](int ks, int bi) {
        const int k0 = ks << 5;
#pragma unroll
        for (int t = 0; t < 2; ++t) {
            const int seg = wave * 2 + t;
            gload_lds16(&A[(size_t)(m0 + seg * 16 + srow) * K + k0 + sk], &As[bi][seg * 512]);
            gload_lds16(&Bw[(size_t)(n0 + seg * 16 + srow) * K + k0 + sk], &Bs[bi][seg * 512]);
        }
    };

    f32x4v acc[4][4];
#pragma unroll
    for (int i = 0; i < 4; ++i)
#pragma unroll
        for (int j = 0; j < 4; ++j)
#pragma unroll
            for (int q = 0; q < 4; ++q) acc[i][j][q] = 0.f;

    const int nk = K >> 5;
    STAGE(0, 0);
    STAGE(1, 1);

    for (int ks = 0; ks < nk; ++ks) {
        // wait for buf[ks]'s loads (issued 2 steps ago); keep later stages in flight
        if (ks < nk - 1) asm volatile("s_waitcnt vmcnt(4)" ::: "memory");
        else             asm volatile("s_waitcnt vmcnt(0)" ::: "memory");
        __builtin_amdgcn_sched_barrier(0);
        __builtin_amdgcn_s_barrier();            // all waves' buf[ks] loads done;
        asm volatile("" ::: "memory");           //  buf[ks-1] readers all finished
        __builtin_amdgcn_sched_barrier(0);

        const unsigned short* Ab = As[ks % 3];
        const unsigned short* Bb = Bs[ks % 3];
        bf16x8 af[4], bfg[4];
#pragma unroll
        for (int i = 0; i < 4; ++i)
            af[i] = *(const bf16x8*)&Ab[(wr + i * 16 + fr) * 32 + swk];
#pragma unroll
        for (int j = 0; j < 4; ++j)
            bfg[j] = *(const bf16x8*)&Bb[(wc + j * 16 + fr) * 32 + swk];

        if (ks + 2 < nk) STAGE(ks + 2, (ks + 2) % 3);   // overwrites buf[ks-1]

        __builtin_amdgcn_s_setprio(1);
#pragma unroll
        for (int i = 0; i < 4; ++i)
#pragma unroll
            for (int j = 0; j < 4; ++j)
                acc[i][j] = __builtin_amdgcn_mfma_f32_16x16x32_bf16(af[i], bfg[j], acc[i][j], 0, 0, 0);
        __builtin_amdgcn_s_setprio(0);
    }

    const int r4 = hi * 4;
    if constexpr (FUSED) {
        const int part = (n0 >> 7) % 3;          // 0=q 1=k 2=v
        const int head = n0 / 384;
        const int bh   = (m0 >> 11) * NHEAD + head;
        if (part == 2) {
            // V: transposed write, 4 consecutive t per frag -> ushort4
#pragma unroll
            for (int i = 0; i < 4; ++i) {
                const int t0v = (m0 & (T_DIM - 1)) + wr + i * 16 + r4;
#pragma unroll
                for (int j = 0; j < 4; ++j) {
                    const int d = wc + j * 16 + fr;
                    const float bv = bias[n0 + d];
                    ushort4 o = make_ushort4(f2bf(acc[i][j][0] + bv), f2bf(acc[i][j][1] + bv),
                                             f2bf(acc[i][j][2] + bv), f2bf(acc[i][j][3] + bv));
                    *(ushort4*)&Vt[((size_t)bh * HS + d) * T_DIM + t0v] = o;
                }
            }
        } else {
            unsigned short* Dst = part ? Kb : Qb;
            if (wc == 0) {
                // rope lanes: cols d=j*16+fr (j<2) paired with d+32 (j+2)
#pragma unroll
                for (int i = 0; i < 4; ++i) {
#pragma unroll
                    for (int q = 0; q < 4; ++q) {
                        const int t = (m0 & (T_DIM - 1)) + wr + i * 16 + r4 + q;
                        const float* crow = &cosb[t * 64];
                        const float* srw  = &sinb[t * 64];
                        unsigned short* drow = &Dst[((size_t)bh * T_DIM + t) * HS];
#pragma unroll
                        for (int j = 0; j < 2; ++j) {
                            const int d = j * 16 + fr;
                            const float v1 = acc[i][j][q]     + bias[n0 + d];
                            const float v2 = acc[i][j + 2][q] + bias[n0 + d + 32];
                            drow[d]      = f2bf(v1 * crow[d]      - v2 * srw[d]);
                            drow[d + 32] = f2bf(v2 * crow[d + 32] + v1 * srw[d + 32]);
                        }
                    }
                }
            } else {
                // non-rope lanes: d = 64 + j*16 + fr
#pragma unroll
                for (int i = 0; i < 4; ++i) {
                    const int t0r = (m0 & (T_DIM - 1)) + wr + i * 16 + r4;
#pragma unroll
                    for (int j = 0; j < 4; ++j) {
                        const int d = 64 + j * 16 + fr;
                        const float bv = bias[n0 + d];
                        unsigned short* dcol = &Dst[((size_t)bh * T_DIM + t0r) * HS + d];
#pragma unroll
                        for (int q = 0; q < 4; ++q)
                            dcol[(size_t)q * HS] = f2bf(acc[i][j][q] + bv);
                    }
                }
            }
        }
    } else {
#pragma unroll
        for (int i = 0; i < 4; ++i) {
#pragma unroll
            for (int j = 0; j < 4; ++j) {
                const int col = n0 + wc + j * 16 + fr;
                const float bv = bias[col];
#pragma unroll
                for (int q = 0; q < 4; ++q) {
                    const int row = m0 + wr + i * 16 + r4 + q;
                    Cf32[(size_t)row * N + col] = acc[i][j][q] + bv;
                }
            }
        }
    }
}

// ---------------------------------------------------------------------------
// adapter qkv (tiny GEMM, bf16 weights; verified R5)
// ---------------------------------------------------------------------------
__global__ __launch_bounds__(64)
void adapter_qkv_kernel(const float* __restrict__ wte, const unsigned short* __restrict__ wb,
                        const float* __restrict__ bias, float* __restrict__ aqkv) {
    const int n = blockIdx.x;
    const int lane = threadIdx.x;
    float acc[AT];
#pragma unroll
    for (int a = 0; a < AT; ++a) acc[a] = 0.f;
    for (int k = lane * 8; k < C_DIM; k += 64 * 8) {
        const ushort4 wa = *(const ushort4*)&wb[(size_t)n * C_DIM + k];
        const ushort4 wc = *(const ushort4*)&wb[(size_t)n * C_DIM + k + 4];
        const float w0 = bf2f(wa.x), w1 = bf2f(wa.y), w2 = bf2f(wa.z), w3 = bf2f(wa.w);
        const float w4 = bf2f(wc.x), w5 = bf2f(wc.y), w6 = bf2f(wc.z), w7 = bf2f(wc.w);
#pragma unroll
        for (int a = 0; a < AT; ++a) {
            const float4 t0 = *(const float4*)&wte[(size_t)a * C_DIM + k];
            const float4 t1 = *(const float4*)&wte[(size_t)a * C_DIM + k + 4];
            acc[a] += w0 * t0.x + w1 * t0.y + w2 * t0.z + w3 * t0.w
                    + w4 * t1.x + w5 * t1.y + w6 * t1.z + w7 * t1.w;
        }
    }
#pragma unroll
    for (int a = 0; a < AT; ++a) {
        float v = acc[a];
        for (int off = 32; off; off >>= 1) v += __shfl_down(v, off);
        if (lane == 0) aqkv[(size_t)a * QKV_N + n] = v + bias[n];
    }
}

// ---------------------------------------------------------------------------
// MFMA flash causal attention (verified R5/R6/R7): qt-paired blocks, dbuf
// staging, log2-domain online softmax with defer-max, in-register P
// redistribution, fused adapter attention, setprio around MFMA.
// ---------------------------------------------------------------------------
__global__ __launch_bounds__(256)
void flash_mfma(const unsigned short* __restrict__ Qb, const unsigned short* __restrict__ Kb,
                const unsigned short* __restrict__ Vt, const float* __restrict__ aqkv,
                const float* __restrict__ gating, unsigned short* __restrict__ yb) {
    __shared__ __align__(16) unsigned short smem[2][16384];   // [buf][K:8192 | V:8192]

    const int tid = threadIdx.x;
    const int wave = tid >> 6, lane = tid & 63;
    const int lo = lane & 15, hi = lane >> 4;

    const int z = blockIdx.x & 15;
    const int h = (blockIdx.x >> 4) & 15;
    const int b = blockIdx.x >> 8;
    const int bh = b * NHEAD + h;
    const float kscale = 0.08838834764831845f * 1.4426950408889634f;  // scale*log2(e)

    const unsigned short* Qh = Qb + (size_t)bh * T_DIM * HS;
    const unsigned short* Kh = Kb + (size_t)bh * T_DIM * HS;
    const unsigned short* Vh = Vt + (size_t)bh * HS * T_DIM;

    float* AK = (float*)&smem[0][0];     // adapter overlay (10x128 f32 x2 = 10KB)
    float* AV = AK + AT * HS;

    auto STAGE = [&](int k0, int bufi) {
        unsigned short* Kd = &smem[bufi][0];
        unsigned short* Vd = &smem[bufi][8192];
#pragma unroll
        for (int t = 0; t < 4; ++t) {
            const int kr = wave * 16 + t * 4 + hi;
            gload_lds16(Kh + (size_t)(k0 + kr) * HS + 8 * (lo ^ (kr & 7)),
                        &Kd[(wave * 16 + t * 4) * 128]);
            const int vr = (wave * 4 + t) * 8 + (lane >> 3);
            gload_lds16(Vh + (size_t)vr * T_DIM + k0 + 8 * ((lane & 7) ^ (vr & 7)),
                        &Vd[(wave * 4 + t) * 8 * 64]);
        }
    };

#pragma unroll 1
    for (int pass = 0; pass < 2; ++pass) {
        const int qt = pass ? z : (31 - z);
        const int q0 = qt * 64;
        const int myqrow = q0 + wave * 16 + lo;

        bf16x8 qf[4];
        {
            const unsigned short* qrow = Qh + (size_t)myqrow * HS;
#pragma unroll
            for (int c = 0; c < 4; ++c) qf[c] = *(const bf16x8*)&qrow[c * 32 + hi * 8];
        }

        f32x4v oacc[8];
#pragma unroll
        for (int d = 0; d < 8; ++d)
#pragma unroll
            for (int q = 0; q < 4; ++q) oacc[d][q] = 0.f;
        float m = -INFINITY, ln = 0.f;

        STAGE(0, 0);
        int cur = 0;
        for (int kt = 0; kt <= qt; ++kt) {
            const int k0 = kt * 64;
            __syncthreads();
            if (kt < qt) STAGE(k0 + 64, cur ^ 1);
            const unsigned short* Ks = &smem[cur][0];
            const unsigned short* Vs = &smem[cur][8192];

            f32x4v sacc[4];
            __builtin_amdgcn_s_setprio(1);
#pragma unroll
            for (int s = 0; s < 4; ++s) {
#pragma unroll
                for (int q = 0; q < 4; ++q) sacc[s][q] = 0.f;
                const int krow = s * 16 + lo;
                const int rs = (lo & 7) << 4;
#pragma unroll
                for (int c = 0; c < 4; ++c) {
                    const int boff = (c * 64 + hi * 16) ^ rs;
                    bf16x8 kf = *(const bf16x8*)&Ks[krow * 128 + (boff >> 1)];
                    sacc[s] = __builtin_amdgcn_mfma_f32_16x16x32_bf16(kf, qf[c], sacc[s], 0, 0, 0);
                }
            }
            __builtin_amdgcn_s_setprio(0);

            const bool dtile = (kt == qt);
            float p[4][4];
            float xm = -INFINITY;
#pragma unroll
            for (int s = 0; s < 4; ++s)
#pragma unroll
                for (int q = 0; q < 4; ++q) {
                    float v = sacc[s][q] * kscale;
                    if (dtile && (k0 + s * 16 + hi * 4 + q > myqrow)) v = -INFINITY;
                    p[s][q] = v;
                    xm = fmaxf(xm, v);
                }
            xm = fmaxf(xm, __shfl_xor(xm, 16));
            xm = fmaxf(xm, __shfl_xor(xm, 32));
            if (__any(xm > m + 11.5f)) {
                const float mnew = fmaxf(m, xm);
                const float al = exp2f(m - mnew);
                m = mnew;
                ln *= al;
                float aq[4];
#pragma unroll
                for (int q = 0; q < 4; ++q) aq[q] = __shfl(al, hi * 4 + q);
#pragma unroll
                for (int d = 0; d < 8; ++d)
#pragma unroll
                    for (int q = 0; q < 4; ++q) oacc[d][q] *= aq[q];
            }
            float psum = 0.f;
#pragma unroll
            for (int s = 0; s < 4; ++s)
#pragma unroll
                for (int q = 0; q < 4; ++q) {
                    p[s][q] = exp2f(p[s][q] - m);
                    psum += p[s][q];
                }
            psum += __shfl_xor(psum, 16);
            psum += __shfl_xor(psum, 32);
            ln += psum;

            unsigned int pk[4][2];
#pragma unroll
            for (int s = 0; s < 4; ++s) {
                pk[s][0] = pack_bf16(p[s][0], p[s][1]);
                pk[s][1] = pack_bf16(p[s][2], p[s][3]);
            }
            const int src0 = lo + ((hi & 1) << 5);
            const int src1 = src0 + 16;
            const bool shi = (hi >> 1) != 0;
#pragma unroll
            for (int c = 0; c < 2; ++c) {
                const unsigned int a0 = (unsigned int)__shfl((int)pk[c*2][0], src0);
                const unsigned int b0 = (unsigned int)__shfl((int)pk[c*2+1][0], src0);
                const unsigned int a1 = (unsigned int)__shfl((int)pk[c*2][1], src0);
                const unsigned int b1 = (unsigned int)__shfl((int)pk[c*2+1][1], src0);
                const unsigned int a2 = (unsigned int)__shfl((int)pk[c*2][0], src1);
                const unsigned int b2 = (unsigned int)__shfl((int)pk[c*2+1][0], src1);
                const unsigned int a3 = (unsigned int)__shfl((int)pk[c*2][1], src1);
                const unsigned int b3 = (unsigned int)__shfl((int)pk[c*2+1][1], src1);
                union { unsigned int u[4]; bf16x8 v; } cv2;
                cv2.u[0] = shi ? b0 : a0;
                cv2.u[1] = shi ? b1 : a1;
                cv2.u[2] = shi ? b2 : a2;
                cv2.u[3] = shi ? b3 : a3;
                const bf16x8 pf = cv2.v;
                __builtin_amdgcn_s_setprio(1);
#pragma unroll
                for (int d = 0; d < 8; ++d) {
                    const int vrow = d * 16 + lo;
                    const int boff = (c * 64 + hi * 16) ^ ((lo & 7) << 4);
                    bf16x8 vf = *(const bf16x8*)&Vs[vrow * 64 + (boff >> 1)];
                    oacc[d] = __builtin_amdgcn_mfma_f32_16x16x32_bf16(pf, vf, oacc[d], 0, 0, 0);
                }
                __builtin_amdgcn_s_setprio(0);
            }
            cur ^= 1;
        }

        float linv[4];
#pragma unroll
        for (int q = 0; q < 4; ++q) linv[q] = 1.f / __shfl(ln, hi * 4 + q);
#pragma unroll
        for (int d = 0; d < 8; ++d)
#pragma unroll
            for (int q = 0; q < 4; ++q) oacc[d][q] *= linv[q];

        // ---- adapter attention (10 keys, unmasked; BLOCKED aqkv layout) ----
        __syncthreads();
        for (int idx = tid; idx < AT * HS; idx += 256) {
            const int a = idx >> 7, d = idx & 127;
            AK[idx] = aqkv[(size_t)a * QKV_N + C_DIM + h * HS + d];
            AV[idx] = aqkv[(size_t)a * QKV_N + 2 * C_DIM + h * HS + d];
        }
        __syncthreads();

        float qflt[4][8];
#pragma unroll
        for (int c = 0; c < 4; ++c)
#pragma unroll
            for (int j = 0; j < 8; ++j) qflt[c][j] = bf2f((unsigned short)qf[c][j]);

        float e[AT];
        float amax = -INFINITY;
#pragma unroll
        for (int a = 0; a < AT; ++a) {
            float t = 0.f;
#pragma unroll
            for (int c = 0; c < 4; ++c) {
                const float4 k0v = *(const float4*)&AK[a * HS + c * 32 + hi * 8];
                const float4 k1v = *(const float4*)&AK[a * HS + c * 32 + hi * 8 + 4];
                t += qflt[c][0] * k0v.x + qflt[c][1] * k0v.y + qflt[c][2] * k0v.z + qflt[c][3] * k0v.w
                   + qflt[c][4] * k1v.x + qflt[c][5] * k1v.y + qflt[c][6] * k1v.z + qflt[c][7] * k1v.w;
            }
            t += __shfl_xor(t, 16);
            t += __shfl_xor(t, 32);
            e[a] = t * 0.08838834764831845f;
            amax = fmaxf(amax, e[a]);
        }
        float asum = 0.f;
#pragma unroll
        for (int a = 0; a < AT; ++a) { e[a] = __expf(e[a] - amax); asum += e[a]; }
        const float gcoef = gating[0] / asum;

#pragma unroll
        for (int a = 0; a < AT; ++a) {
            const float ca = e[a] * gcoef;
            float cq[4];
#pragma unroll
            for (int q = 0; q < 4; ++q) cq[q] = __shfl(ca, hi * 4 + q);
#pragma unroll
            for (int d = 0; d < 8; ++d) {
                const float av = AV[a * HS + d * 16 + lo];
#pragma unroll
                for (int q = 0; q < 4; ++q) oacc[d][q] += cq[q] * av;
            }
        }

#pragma unroll
        for (int q = 0; q < 4; ++q) {
            const int row = q0 + wave * 16 + hi * 4 + q;
            unsigned short* dst = yb + ((size_t)(b * T_DIM + row)) * C_DIM + h * HS + lo;
#pragma unroll
            for (int d = 0; d < 8; ++d) dst[d * 16] = f2bf(oacc[d][q]);
        }

        if (pass == 0) __syncthreads();
    }
}

// ---------------------------------------------------------------------------
extern "C" void kernel_launch(void* const* d_in, const int* in_sizes, int n_in,
                              void* d_out, int out_size, void* d_ws, size_t ws_size,
                              hipStream_t stream) {
    const float* x       = (const float*)d_in[0];
    const float* cosb    = (const float*)d_in[1];
    const float* sinb    = (const float*)d_in[2];
    // d_in[3] = mask (causal, unused)
    const float* attn_w  = (const float*)d_in[4];
    const float* attn_b  = (const float*)d_in[5];
    const float* proj_w  = (const float*)d_in[6];
    const float* proj_b  = (const float*)d_in[7];
    const float* wte     = (const float*)d_in[8];
    const float* gating  = (const float*)d_in[9];
    float* out = (float*)d_out;

    // workspace (~118 MB): aqkv | xb | awb | Qb | Kb | Vt | pwb | yv
    float* aqkv = (float*)d_ws;
    unsigned short* xb  = (unsigned short*)(aqkv + (size_t)AT * QKV_N);
    unsigned short* awb = xb  + (size_t)M_DIM * C_DIM;
    unsigned short* Qb  = awb + (size_t)QKV_N * C_DIM;
    unsigned short* Kb  = Qb  + (size_t)B_DIM * NHEAD * T_DIM * HS;
    unsigned short* Vt  = Kb  + (size_t)B_DIM * NHEAD * T_DIM * HS;
    unsigned short* pwb = Vt  + (size_t)B_DIM * NHEAD * T_DIM * HS;
    unsigned short* yv  = pwb + (size_t)C_DIM * C_DIM;

    // 1. convert x, attn_w to bf16
    f32_to_bf16_kernel<<<(M_DIM * C_DIM / 8 + 255) / 256, 256, 0, stream>>>(x, xb, M_DIM * C_DIM / 8);
    f32_to_bf16_kernel<<<(QKV_N * C_DIM / 8 + 255) / 256, 256, 0, stream>>>(attn_w, awb, QKV_N * C_DIM / 8);
    // 2. fused qkv GEMM: bias + RoPE + repack -> Qb/Kb/Vt directly
    gemm_pipe<1><<<dim3(QKV_N / 128, M_DIM / 128), 256, 0, stream>>>(
        xb, awb, attn_b, nullptr, cosb, sinb, Qb, Kb, Vt, M_DIM, QKV_N, C_DIM);
    // 3. adapter qkv (bf16 weights)
    adapter_qkv_kernel<<<QKV_N, 64, 0, stream>>>(wte, awb, attn_b, aqkv);
    // 4. convert proj_w
    f32_to_bf16_kernel<<<(C_DIM * C_DIM / 8 + 255) / 256, 256, 0, stream>>>(proj_w, pwb, C_DIM * C_DIM / 8);
    // 5. MFMA flash attention + adapter + gating -> yv (bf16)
    flash_mfma<<<B_DIM * NHEAD * 16, 256, 0, stream>>>(Qb, Kb, Vt, aqkv, gating, yv);
    // 6. out = y @ proj_w^T + proj_b (f32 out)
    gemm_pipe<0><<<dim3(C_DIM / 128, M_DIM / 128), 256, 0, stream>>>(
        yv, pwb, proj_b, out, nullptr, nullptr, nullptr, nullptr, nullptr, M_DIM, C_DIM, C_DIM);
}